// Round 10
// baseline (8486.713 us; speedup 1.0000x reference)
//
#include <hip/hip_runtime.h>
#include <hip/hip_bf16.h>

// ---------------- problem constants ----------------
#define EMBN   512
#define HIDN   1024
#define OUTN   512
#define BBN    64
#define SSN    256
#define NBLK   256          // persistent blocks; block j owns 4 h-dims x 4 gates = 16 preact cols
#define PSTR   20           // preact LDS row stride (floats)

typedef __attribute__((ext_vector_type(8))) short bf16x8;
typedef __attribute__((ext_vector_type(4))) float f32x4;
typedef __attribute__((ext_vector_type(4))) unsigned int u32x4;
typedef unsigned short us;
typedef unsigned long long ull;

static __device__ __forceinline__ us f2bf(float x) {
  unsigned int u = __float_as_uint(x);
  unsigned int r = (u + 0x7fffu + ((u >> 16) & 1u)) >> 16;   // RNE
  return (us)r;
}
static __device__ __forceinline__ float bf2f(us u) {
  unsigned int v = ((unsigned int)u) << 16;
  return __uint_as_float(v);
}

// ---------------- weight prepack: [j(256)][kt(48)][lane(64)][8] ----------------
// block j owns preact cols p = 16j+q, q in [0,16): gate g=q>>2, r=q&3, hd=4j+r
__global__ void pack_w(const float* __restrict__ wxi, const float* __restrict__ wxf,
                       const float* __restrict__ wxo, const float* __restrict__ wxc,
                       const float* __restrict__ whi, const float* __restrict__ whf,
                       const float* __restrict__ who, const float* __restrict__ whc,
                       us* __restrict__ Whip, us* __restrict__ Wlop) {
  int idx = blockIdx.x * 256 + threadIdx.x;       // 256*48*64 = 786432
  int lane = idx & 63;
  int kt   = (idx >> 6) % 48;
  int j    = idx / (48 * 64);
  int q = lane & 15, g = q >> 2, r = q & 3;
  int hd = 4 * j + r;
  int kb = kt * 32 + ((lane >> 4) << 3);
  const float* wx = (g == 0) ? wxi : (g == 1) ? wxf : (g == 2) ? wxo : wxc;
  const float* wh = (g == 0) ? whi : (g == 1) ? whf : (g == 2) ? who : whc;
  long obase = (long)idx * 8;
  #pragma unroll
  for (int jj = 0; jj < 8; ++jj) {
    int k = kb + jj;
    float v = (k < EMBN) ? wx[(long)k * HIDN + hd] : wh[(long)(k - EMBN) * HIDN + hd];
    us hi = f2bf(v);
    us lo = f2bf(v - bf2f(hi));
    Whip[obase + jj] = hi;
    Wlop[obase + jj] = lo;
  }
}

// ---------------- embedding gather + hi/lo split: X[t][b][k] ----------------
__global__ void pack_x(const int* __restrict__ tokens, const float* __restrict__ emb,
                       us* __restrict__ Xhi, us* __restrict__ Xlo) {
  int idx = blockIdx.x * 256 + threadIdx.x;       // 256*64*512 = 8388608
  int k = idx & 511;
  int b = (idx >> 9) & 63;
  int t = idx >> 15;
  int tok = tokens[b * SSN + t];
  float v = emb[(long)tok * EMBN + k];
  us hi = f2bf(v);
  Xhi[idx] = hi;
  Xlo[idx] = f2bf(v - bf2f(hi));
}

// chunk = 4 kt (4 hi + 4 lo frags = 8 bf16x8 = 32 VGPR)
#define XISS(A, c) { _Pragma("unroll") for (int q = 0; q < 4; ++q) { \
      A[2*q]   = *(const bf16x8*)(xh + (((c)*4 + q) << 5)); \
      A[2*q+1] = *(const bf16x8*)(xl + (((c)*4 + q) << 5)); } }
#define XCON(A, c) { _Pragma("unroll") for (int q = 0; q < 4; ++q) { \
      const int kt = (c)*4 + q; \
      bf16x8 w0 = *(const bf16x8*)(WHi + (kt << 9) + (lane << 3)); \
      bf16x8 w1 = *(const bf16x8*)(WLo + (kt << 9) + (lane << 3)); \
      accA = __builtin_amdgcn_mfma_f32_16x16x32_bf16(w0, A[2*q],   accA, 0, 0, 0); \
      accB = __builtin_amdgcn_mfma_f32_16x16x32_bf16(w0, A[2*q+1], accB, 0, 0, 0); \
      accC = __builtin_amdgcn_mfma_f32_16x16x32_bf16(w1, A[2*q],   accC, 0, 0, 0); } }

// H load (CACHED, L2-shared) with sentinel capture: producer stores are 8B-atomic;
// checking u32 lanes .x/.z of each 16B covers both embedded 8B quads. Data can
// never equal 0xFFFFFFFF (two bf16 NaNs can't come out of f2bf(finite)).
#define HLD(A, S, c) { _Pragma("unroll") for (int q = 0; q < 4; ++q) { \
      const int ct = (c)*4 + q; \
      u32x4 rh = *(const u32x4*)(hh + (ct << 5)); \
      u32x4 rl = *(const u32x4*)(hl + (ct << 5)); \
      A[2*q]   = *(bf16x8*)&rh; \
      A[2*q+1] = *(bf16x8*)&rl; \
      unsigned int m0 = rh.x > rh.z ? rh.x : rh.z; \
      unsigned int m1 = rl.x > rl.z ? rl.x : rl.z; \
      S[q] = m0 > m1 ? m0 : m1; } }
// retry: agent acquire-fence (invalidates stale L1/L2 lines) + CACHED reload.
// One RT per retry, preserves L2 sharing for all subsequent readers on this XCD.
#define HCHK(A, S, c) { \
      unsigned int m01 = S[0] > S[1] ? S[0] : S[1]; \
      unsigned int m23 = S[2] > S[3] ? S[2] : S[3]; \
      unsigned int mm  = m01 > m23 ? m01 : m23; \
      while (__builtin_expect(__any(mm == 0xffffffffu), 0)) { \
        __builtin_amdgcn_s_sleep(4); \
        __builtin_amdgcn_fence(__ATOMIC_ACQUIRE, "agent"); \
        HLD(A, S, c) \
        m01 = S[0] > S[1] ? S[0] : S[1]; \
        m23 = S[2] > S[3] ? S[2] : S[3]; \
        mm  = m01 > m23 ? m01 : m23; } }
#define HCON(A, c) { _Pragma("unroll") for (int q = 0; q < 4; ++q) { \
      const int kt = 16 + (c)*4 + q; \
      bf16x8 w0 = *(const bf16x8*)(WHi + (kt << 9) + (lane << 3)); \
      bf16x8 w1 = *(const bf16x8*)(WLo + (kt << 9) + (lane << 3)); \
      accA = __builtin_amdgcn_mfma_f32_16x16x32_bf16(w0, A[2*q],   accA, 0, 0, 0); \
      accB = __builtin_amdgcn_mfma_f32_16x16x32_bf16(w0, A[2*q+1], accB, 0, 0, 0); \
      accC = __builtin_amdgcn_mfma_f32_16x16x32_bf16(w1, A[2*q],   accC, 0, 0, 0); } }

// ---------------- persistent LSTM recurrence ----------------
// 256 blocks x 256 threads (4 waves, one per SIMD). Wave wv = batches [16wv,16wv+16).
// ROUND-9: ZERO flags / acks / polls. The H ring is sentinel-prefilled (0xFF);
// consumers use CACHED loads (L2-shared broadcast) validated per 8B quad; on a
// sentinel hit: acquire-fence + cached reload (rare in steady state). Producers
// just store h quads (agent scope -> IF$) and proceed — no waits at all.
// Serial cost/step collapses from ~4 coherent round trips to ~1 (the H load).
// Safety arguments:
//  * skew <= 1 step: a block at step t consumed h(t), which required every
//    producer to have finished step t-1 -> re-sentinel of slot (t+2)%K (K>=8)
//    touches a slot all blocks finished reading >= 5 steps ago.
//  * sentinel(t+2) vs data(t+2) ordering: between the two stores lies step
//    t+1's H phase, whose vmcnt waits drain all OLDER vmem ops (hw counter
//    semantics) -> sentinel is in IF$ long before the data store issues.
//  * L2 staleness across ring reuse: one acquire-fence per wrap (t%K==0)
//    invalidates L2 before any slot line is re-read.
__launch_bounds__(256, 1)
__global__ void lstm_persist(const us* __restrict__ Whip, const us* __restrict__ Wlop,
                             const us* __restrict__ Xhi, const us* __restrict__ Xlo,
                             us* Hhi, us* Hlo, float* hfin,
                             const float* __restrict__ biP, const float* __restrict__ bfP,
                             const float* __restrict__ boP, const float* __restrict__ bcP,
                             int K) {
  extern __shared__ char smem[];
  us* WHi = (us*)smem;                         // 24576 shorts
  us* WLo = WHi + 24576;                       // 24576 shorts
  float* preact = (float*)(smem + 98304);      // [64][PSTR], rows partition by wave

  const int j = blockIdx.x, tid = threadIdx.x;
  const int wv = tid >> 6, lane = tid & 63;
  const int Km = K - 1;
  const bool ROT = (K != 256);

  // one-time: W slices -> LDS (fragment layout identical, straight copy)
  {
    const uint4* shi = (const uint4*)(Whip + (long)j * 24576);
    const uint4* slo = (const uint4*)(Wlop + (long)j * 24576);
    uint4* dhi = (uint4*)WHi;
    uint4* dlo = (uint4*)WLo;
    for (int i = tid; i < 3072; i += 256) { dhi[i] = shi[i]; dlo[i] = slo[i]; }
  }
  // gate mapping: thread -> (b = tid>>2, r = tid&3); c-state in register.
  const int gb = tid >> 2, gr = tid & 3;
  const float bi_r = biP[4 * j + gr], bf_r = bfP[4 * j + gr];
  const float bo_r = boP[4 * j + gr], bc_r = bcP[4 * j + gr];
  float c_reg = 0.f;

  const int mrow = (wv << 4) + (lane & 15);    // batch row (MFMA N-dim)
  const int kj = (lane >> 4) << 3;
  const int p0 = (lane >> 4) << 2;
  __syncthreads();                             // W in LDS ready (only barrier)

  f32x4 accA = {0.f, 0.f, 0.f, 0.f};
  f32x4 accB = {0.f, 0.f, 0.f, 0.f};
  f32x4 accC = {0.f, 0.f, 0.f, 0.f};

  // ---- prologue: acc = X(0) contribution ----
  {
    const us* xh = Xhi + (mrow << 9) + kj;
    const us* xl = Xlo + (mrow << 9) + kj;
    bf16x8 XA[8], XB[8];
    XISS(XA, 0) XISS(XB, 1)
    __builtin_amdgcn_sched_barrier(0);
    XCON(XA, 0) XISS(XA, 2)
    __builtin_amdgcn_sched_barrier(0);
    XCON(XB, 1) XISS(XB, 3)
    __builtin_amdgcn_sched_barrier(0);
    XCON(XA, 2) XCON(XB, 3)
  }

  #pragma unroll 1
  for (int t = 0; t < SSN; ++t) {
    if (t > 0) {
      if (ROT && (t & Km) == 0)
        __builtin_amdgcn_fence(__ATOMIC_ACQUIRE, "agent");  // ring wrap: drop stale L1/L2

      // ---- H part: cached sentinel-validated loads, 4-deep load/MFMA pipeline ----
      const int cur = t & Km;
      const us* hh = Hhi + (((long)cur * BBN + mrow) << 10) + kj;
      const us* hl = Hlo + (((long)cur * BBN + mrow) << 10) + kj;
      bf16x8 HA[8], HB[8], HC[8], HD[8];
      unsigned int SA[4], SB_[4], SC[4], SD[4];
      HLD(HA, SA, 0) HLD(HB, SB_, 1) HLD(HC, SC, 2) HLD(HD, SD, 3)
      __builtin_amdgcn_sched_barrier(0);
      HCHK(HA, SA, 0)  HCON(HA, 0) HLD(HA, SA, 4)
      __builtin_amdgcn_sched_barrier(0);
      HCHK(HB, SB_, 1) HCON(HB, 1) HLD(HB, SB_, 5)
      __builtin_amdgcn_sched_barrier(0);
      HCHK(HC, SC, 2)  HCON(HC, 2) HLD(HC, SC, 6)
      __builtin_amdgcn_sched_barrier(0);
      HCHK(HD, SD, 3)  HCON(HD, 3) HLD(HD, SD, 7)
      __builtin_amdgcn_sched_barrier(0);
      HCHK(HA, SA, 4)  HCON(HA, 4)
      HCHK(HB, SB_, 5) HCON(HB, 5)
      HCHK(HC, SC, 6)  HCON(HC, 6)
      HCHK(HD, SD, 7)  HCON(HD, 7)

      // small-ring: re-sentinel own slice of slot t+2 (ordered vs its future
      // data store by step t+1's H-phase vmcnt waits; slot idle: skew<=1).
      if (ROT && t + 2 >= K && t + 2 < SSN && gr == 0) {
        const long snt = (long)((t + 2) & Km);
        __hip_atomic_store((ull*)(Hhi + ((snt * BBN + gb) << 10) + 4 * j), ~0ull,
                           __ATOMIC_RELAXED, __HIP_MEMORY_SCOPE_AGENT);
        __hip_atomic_store((ull*)(Hlo + ((snt * BBN + gb) << 10) + 4 * j), ~0ull,
                           __ATOMIC_RELAXED, __HIP_MEMORY_SCOPE_AGENT);
      }
    }

    // ---- preact: lane holds D[p0+rg][mrow]; 16B LDS store (intra-wave rows) ----
    {
      f32x4 acc = accA + accB;
      acc = acc + accC;
      *(f32x4*)(preact + mrow * PSTR + p0) = acc;
    }
    // no barrier: producer lanes and consumer threads are the SAME wave.

    // ---- gates: one (b,r) per thread ----
    {
      float pi = preact[gb * PSTR + gr]      + bi_r;
      float pf = preact[gb * PSTR + 4 + gr]  + bf_r;
      float po = preact[gb * PSTR + 8 + gr]  + bo_r;
      float pc = preact[gb * PSTR + 12 + gr] + bc_r;
      float vi = 1.f / (1.f + expf(-pi));
      float vf = 1.f / (1.f + expf(-pf));
      float vo = 1.f / (1.f + expf(-po));
      float vc = tanhf(pc);
      c_reg = vf * c_reg + vi * vc;
      float h = vo * tanhf(c_reg);

      if (t == SSN - 1) {
        hfin[(gb << 10) + 4 * j + gr] = h;     // last step: only the final h matters
      } else {
        us hh_ = f2bf(h);
        us hl_ = f2bf(h - bf2f(hh_));
        // pack (hi,lo) of the 4 dims of this lane-group into two 8B quads
        unsigned int hpair = (unsigned int)hh_ | ((unsigned int)hl_ << 16);
        const int base = lane & ~3;
        unsigned int g0 = (unsigned int)__shfl((int)hpair, base);
        unsigned int g1 = (unsigned int)__shfl((int)hpair, base + 1);
        unsigned int g2 = (unsigned int)__shfl((int)hpair, base + 2);
        unsigned int g3 = (unsigned int)__shfl((int)hpair, base + 3);
        unsigned int hi01 = (g0 & 0xffffu) | (g1 << 16);
        unsigned int hi23 = (g2 & 0xffffu) | (g3 << 16);
        unsigned int lo01 = (g0 >> 16)     | (g1 & 0xffff0000u);
        unsigned int lo23 = (g2 >> 16)     | (g3 & 0xffff0000u);
        ull hiq = ((ull)hi23 << 32) | (ull)hi01;
        ull loq = ((ull)lo23 << 32) | (ull)lo01;

        const long nxt = (long)((t + 1) & Km);
        if (gr == 0) {
          __hip_atomic_store((ull*)(Hhi + ((nxt * BBN + gb) << 10) + 4 * j), hiq,
                             __ATOMIC_RELAXED, __HIP_MEMORY_SCOPE_AGENT);
          __hip_atomic_store((ull*)(Hlo + ((nxt * BBN + gb) << 10) + 4 * j), loq,
                             __ATOMIC_RELAXED, __HIP_MEMORY_SCOPE_AGENT);
        }
        // NO ack, NO flag: stores drain to IF$ while we run X(t+1).

        // ---- X part for t+1 ----
        const us* xh = Xhi + ((long)(t + 1) << 15) + (mrow << 9) + kj;
        const us* xl = Xlo + ((long)(t + 1) << 15) + (mrow << 9) + kj;
        bf16x8 XA[8], XB[8];
        XISS(XA, 0) XISS(XB, 1)
        __builtin_amdgcn_sched_barrier(0);
        accA = {0.f, 0.f, 0.f, 0.f};
        accB = {0.f, 0.f, 0.f, 0.f};
        accC = {0.f, 0.f, 0.f, 0.f};
        XCON(XA, 0) XISS(XA, 2)
        __builtin_amdgcn_sched_barrier(0);
        XCON(XB, 1) XISS(XB, 3)
        __builtin_amdgcn_sched_barrier(0);
        XCON(XA, 2) XCON(XB, 3)
      }
    }
  }
}

// ---------------- output GEMM: out = h_S @ W_hy + b_hy (fp32) ----------------
__global__ void out_gemm(const float* __restrict__ hfin, const float* __restrict__ Why,
                         const float* __restrict__ bhy, float* __restrict__ out) {
  int b = blockIdx.x, n = threadIdx.x;
  const float* h = hfin + (b << 10);
  float acc = 0.f;
  #pragma unroll 8
  for (int k = 0; k < HIDN; ++k) acc = fmaf(h[k], Why[(k << 9) + n], acc);
  out[(b << 9) + n] = acc + bhy[n];
}

// ---------------- launch ----------------
extern "C" void kernel_launch(void* const* d_in, const int* in_sizes, int n_in,
                              void* d_out, int out_size, void* d_ws, size_t ws_size,
                              hipStream_t stream) {
  const int*   tokens = (const int*)d_in[0];
  const float* emb    = (const float*)d_in[1];
  const float* Wxi    = (const float*)d_in[2];
  const float* Wxf    = (const float*)d_in[3];
  const float* Wxo    = (const float*)d_in[4];
  const float* Wxc    = (const float*)d_in[5];
  const float* Whi_   = (const float*)d_in[6];
  const float* Whf    = (const float*)d_in[7];
  const float* Who    = (const float*)d_in[8];
  const float* Whc    = (const float*)d_in[9];
  const float* Why    = (const float*)d_in[10];
  const float* bi     = (const float*)d_in[11];
  const float* bfv    = (const float*)d_in[12];
  const float* bo     = (const float*)d_in[13];
  const float* bc     = (const float*)d_in[14];
  const float* bhy    = (const float*)d_in[15];
  float* outp = (float*)d_out;

  char* ws = (char*)d_ws;
  size_t off = 0;
  auto carve = [&](size_t bytes) -> void* {
    void* p = ws + off;
    off += (bytes + 255) & ~(size_t)255;
    return p;
  };
  us*    Whip = (us*)carve(12582912);
  us*    Wlop = (us*)carve(12582912);
  us*    Xhi  = (us*)carve(16777216);
  us*    Xlo  = (us*)carve(16777216);
  float* hfin = (float*)carve(262144);

  // ring depth: largest power-of-two slot count (8..256) that fits.
  // K=256 -> every slot written once (no re-sentinel, no wrap fences).
  size_t rem = (ws_size > off) ? (ws_size - off) : 0;
  int K = 256;
  while (K > 8 && (size_t)2 * (size_t)K * 131072 + 512 > rem) K >>= 1;
  if ((size_t)2 * (size_t)K * 131072 + 512 > rem) {
    (void)hipMemsetAsync(d_out, 0, (size_t)out_size * 4, stream);  // workspace too small
    return;
  }
  us* Hhi = (us*)carve((size_t)K * 131072);
  us* Hlo = (us*)carve((size_t)K * 131072);

  // sentinel prefill: 0xFF bytes = bf16 NaN pairs, unproducible by f2bf(finite)
  (void)hipMemsetAsync(Hhi, 0xFF, (size_t)K * 131072, stream);
  (void)hipMemsetAsync(Hlo, 0xFF, (size_t)K * 131072, stream);

  pack_w<<<3072, 256, 0, stream>>>(Wxi, Wxf, Wxo, Wxc, Whi_, Whf, Who, Whc, Whip, Wlop);
  pack_x<<<32768, 256, 0, stream>>>(tokens, emb, Xhi, Xlo);

  (void)hipFuncSetAttribute((const void*)lstm_persist,
                            hipFuncAttributeMaxDynamicSharedMemorySize, 103424);
  lstm_persist<<<NBLK, 256, 103424, stream>>>(Whip, Wlop, Xhi, Xlo, Hhi, Hlo,
                                              hfin, bi, bfv, bo, bc, K);
  out_gemm<<<BBN, OUTN, 0, stream>>>(hfin, Why, bhy, outp);
}

// Round 11
// 2921.505 us; speedup vs baseline: 2.9049x; 2.9049x over previous
//
#include <hip/hip_runtime.h>
#include <hip/hip_bf16.h>

// ---------------- problem constants ----------------
#define EMBN   512
#define HIDN   1024
#define OUTN   512
#define BBN    64
#define SSN    256
#define NBLK   128          // persistent blocks; block j owns 8 h-dims x 4 gates = 32 preact cols
#define PST2   36           // preact LDS row stride (floats), 32 cols + pad

typedef __attribute__((ext_vector_type(8))) short bf16x8;
typedef __attribute__((ext_vector_type(4))) float f32x4;
typedef __attribute__((ext_vector_type(4))) int int4v;
typedef unsigned short us;
typedef unsigned long long ull;

static __device__ __forceinline__ us f2bf(float x) {
  unsigned int u = __float_as_uint(x);
  unsigned int r = (u + 0x7fffu + ((u >> 16) & 1u)) >> 16;   // RNE
  return (us)r;
}
static __device__ __forceinline__ float bf2f(us u) {
  unsigned int v = ((unsigned int)u) << 16;
  return __uint_as_float(v);
}

// ---------------- weight prepack: [v(256)][kt(48)][lane(64)][8] ----------------
// UNCHANGED layout: virtual block v owns preact cols p = 16v+q, q in [0,16):
// gate g=q>>2, r=q&3, hd=4v+r. Runtime block j uses virtual blocks 2j, 2j+1.
__global__ void pack_w(const float* __restrict__ wxi, const float* __restrict__ wxf,
                       const float* __restrict__ wxo, const float* __restrict__ wxc,
                       const float* __restrict__ whi, const float* __restrict__ whf,
                       const float* __restrict__ who, const float* __restrict__ whc,
                       us* __restrict__ Whip, us* __restrict__ Wlop) {
  int idx = blockIdx.x * 256 + threadIdx.x;       // 256*48*64 = 786432
  int lane = idx & 63;
  int kt   = (idx >> 6) % 48;
  int v    = idx / (48 * 64);
  int q = lane & 15, g = q >> 2, r = q & 3;
  int hd = 4 * v + r;
  int kb = kt * 32 + ((lane >> 4) << 3);
  const float* wx = (g == 0) ? wxi : (g == 1) ? wxf : (g == 2) ? wxo : wxc;
  const float* wh = (g == 0) ? whi : (g == 1) ? whf : (g == 2) ? who : whc;
  long obase = (long)idx * 8;
  #pragma unroll
  for (int jj = 0; jj < 8; ++jj) {
    int k = kb + jj;
    float val = (k < EMBN) ? wx[(long)k * HIDN + hd] : wh[(long)(k - EMBN) * HIDN + hd];
    us hi = f2bf(val);
    us lo = f2bf(val - bf2f(hi));
    Whip[obase + jj] = hi;
    Wlop[obase + jj] = lo;
  }
}

// ---------------- embedding gather + hi/lo split: X[t][b][k] ----------------
__global__ void pack_x(const int* __restrict__ tokens, const float* __restrict__ emb,
                       us* __restrict__ Xhi, us* __restrict__ Xlo) {
  int idx = blockIdx.x * 256 + threadIdx.x;       // 256*64*512 = 8388608
  int k = idx & 511;
  int b = (idx >> 9) & 63;
  int t = idx >> 15;
  int tok = tokens[b * SSN + t];
  float v = emb[(long)tok * EMBN + k];
  us hi = f2bf(v);
  Xhi[idx] = hi;
  Xlo[idx] = f2bf(v - bf2f(hi));
}

// ---- fragment-load macros (X/H data; unchanged) ----
#define XISS(A, c) { _Pragma("unroll") for (int q = 0; q < 4; ++q) { \
      A[2*q]   = *(const bf16x8*)(xh + (((c)*4 + q) << 5)); \
      A[2*q+1] = *(const bf16x8*)(xl + (((c)*4 + q) << 5)); } }
#define HISS(A, c) { _Pragma("unroll") for (int q = 0; q < 4; ++q) { \
      A[2*q]   = *(const bf16x8*)(hh + (((c)*4 + q) << 5)); \
      A[2*q+1] = *(const bf16x8*)(hl + (((c)*4 + q) << 5)); } }

// ---- dual-col-tile MFMA macros: v0 W from LDS; v1 W from regs (kt<22) or LDS ----
#define XCON2(A, c) { _Pragma("unroll") for (int q = 0; q < 4; ++q) { \
      const int kt = (c)*4 + q; \
      bf16x8 w0h = *(const bf16x8*)(W0Hi + (kt << 9) + (lane << 3)); \
      bf16x8 w0l = *(const bf16x8*)(W0Lo + (kt << 9) + (lane << 3)); \
      a0A = __builtin_amdgcn_mfma_f32_16x16x32_bf16(w0h, A[2*q],   a0A, 0, 0, 0); \
      a0B = __builtin_amdgcn_mfma_f32_16x16x32_bf16(w0h, A[2*q+1], a0B, 0, 0, 0); \
      a0C = __builtin_amdgcn_mfma_f32_16x16x32_bf16(w0l, A[2*q],   a0C, 0, 0, 0); \
      bf16x8 w1h = RW[2*kt], w1l = RW[2*kt+1]; \
      a1A = __builtin_amdgcn_mfma_f32_16x16x32_bf16(w1h, A[2*q],   a1A, 0, 0, 0); \
      a1B = __builtin_amdgcn_mfma_f32_16x16x32_bf16(w1h, A[2*q+1], a1B, 0, 0, 0); \
      a1C = __builtin_amdgcn_mfma_f32_16x16x32_bf16(w1l, A[2*q],   a1C, 0, 0, 0); } }
#define HCON2(A, c) { _Pragma("unroll") for (int q = 0; q < 4; ++q) { \
      const int kt = 16 + (c)*4 + q; \
      bf16x8 w0h = *(const bf16x8*)(W0Hi + (kt << 9) + (lane << 3)); \
      bf16x8 w0l = *(const bf16x8*)(W0Lo + (kt << 9) + (lane << 3)); \
      a0A = __builtin_amdgcn_mfma_f32_16x16x32_bf16(w0h, A[2*q],   a0A, 0, 0, 0); \
      a0B = __builtin_amdgcn_mfma_f32_16x16x32_bf16(w0h, A[2*q+1], a0B, 0, 0, 0); \
      a0C = __builtin_amdgcn_mfma_f32_16x16x32_bf16(w0l, A[2*q],   a0C, 0, 0, 0); \
      bf16x8 w1h, w1l; \
      if (kt < 22) { w1h = RW[2*kt]; w1l = RW[2*kt+1]; } \
      else { w1h = *(const bf16x8*)(W1Hi + ((kt - 22) << 9) + (lane << 3)); \
             w1l = *(const bf16x8*)(W1Lo + ((kt - 22) << 9) + (lane << 3)); } \
      a1A = __builtin_amdgcn_mfma_f32_16x16x32_bf16(w1h, A[2*q],   a1A, 0, 0, 0); \
      a1B = __builtin_amdgcn_mfma_f32_16x16x32_bf16(w1h, A[2*q+1], a1B, 0, 0, 0); \
      a1C = __builtin_amdgcn_mfma_f32_16x16x32_bf16(w1l, A[2*q],   a1C, 0, 0, 0); } }

// ---------------- persistent LSTM recurrence (C=32: half the blocks) ----------------
// 128 blocks x 256 threads (4 waves). Wave wv = batches [16wv,16wv+16).
// RATIONALE (round-10): round-4's zero-sync per-step-dispatch executed at the
// SAME ~11-12 us/step as the flagged persistent kernel -> sync is ~1 us; the
// step is bound by the L2 broadcast (each block reads ALL of X[t]+H: 384 KB;
// 32 blocks/XCD = 12 MB/step/XCD). Halving the block count halves that traffic.
// W capacity: v0's 96 KB in LDS as before; v1's 96 KB split 52 KB LDS (kt>=22)
// + 44 tiles in per-lane VGPRs (kt<22, 176 regs, statically indexed).
// X/H fragments already in registers feed BOTH col-tiles' MFMAs -> no extra
// data traffic. Sync protocol byte-identical to round-2 (best verified).
__launch_bounds__(256, 1)
__global__ void lstm_persist(const us* __restrict__ Whip, const us* __restrict__ Wlop,
                             const us* __restrict__ Xhi, const us* __restrict__ Xlo,
                             us* Hhi, us* Hlo, float* hfin, int* flags,
                             const float* __restrict__ biP, const float* __restrict__ bfP,
                             const float* __restrict__ boP, const float* __restrict__ bcP,
                             int K) {
  extern __shared__ char smem[];
  us* W0Hi = (us*)smem;                        // 49152 B
  us* W0Lo = (us*)(smem + 49152);              // 49152 B
  us* W1Hi = (us*)(smem + 98304);              // 26624 B (kt 22..48)
  us* W1Lo = (us*)(smem + 124928);             // 26624 B
  float* preact = (float*)(smem + 151552);     // [64][PST2] = 9216 B -> total 160768

  const int j = blockIdx.x, tid = threadIdx.x;
  const int wv = tid >> 6, lane = tid & 63;
  const int Km = K - 1;
  const bool ROT = (K != 256);
  const long v0 = 2 * j, v1 = 2 * j + 1;

  // one-time LDS fills
  {
    const uint4* s0h = (const uint4*)(Whip + v0 * 24576);
    const uint4* s0l = (const uint4*)(Wlop + v0 * 24576);
    uint4* d0h = (uint4*)W0Hi;
    uint4* d0l = (uint4*)W0Lo;
    for (int i = tid; i < 3072; i += 256) { d0h[i] = s0h[i]; d0l[i] = s0l[i]; }
    const uint4* s1h = (const uint4*)(Whip + v1 * 24576 + 11264);  // kt 22..48
    const uint4* s1l = (const uint4*)(Wlop + v1 * 24576 + 11264);
    uint4* d1h = (uint4*)W1Hi;
    uint4* d1l = (uint4*)W1Lo;
    for (int i = tid; i < 1664; i += 256) { d1h[i] = s1h[i]; d1l[i] = s1l[i]; }
  }
  // one-time per-lane register tiles for v1, kt 0..22 (static indexing -> VGPRs)
  bf16x8 RW[44];
  {
    const us* rwh = Whip + v1 * 24576 + (lane << 3);
    const us* rwl = Wlop + v1 * 24576 + (lane << 3);
    #pragma unroll
    for (int i = 0; i < 22; ++i) {
      RW[2*i]   = *(const bf16x8*)(rwh + (i << 9));
      RW[2*i+1] = *(const bf16x8*)(rwl + (i << 9));
    }
  }

  // gate mapping: thread -> (b = tid>>2, r = tid&3) for dims d0=8j+r, d1=8j+4+r
  const int gb = tid >> 2, gr = tid & 3;
  const float bi_0 = biP[8*j + gr],     bf_0 = bfP[8*j + gr];
  const float bo_0 = boP[8*j + gr],     bc_0 = bcP[8*j + gr];
  const float bi_1 = biP[8*j + 4 + gr], bf_1 = bfP[8*j + 4 + gr];
  const float bo_1 = boP[8*j + 4 + gr], bc_1 = bcP[8*j + 4 + gr];
  float c0 = 0.f, c1 = 0.f;

  const int mrow = (wv << 4) + (lane & 15);    // batch row (MFMA N-dim)
  const int kj = (lane >> 4) << 3;
  const int p0 = (lane >> 4) << 2;
  int* const flagsP = flags + (wv << 7);       // this plane's 128 flags
  __syncthreads();                             // W in LDS ready (only barrier)

  f32x4 a0A = {0.f,0.f,0.f,0.f}, a0B = {0.f,0.f,0.f,0.f}, a0C = {0.f,0.f,0.f,0.f};
  f32x4 a1A = {0.f,0.f,0.f,0.f}, a1B = {0.f,0.f,0.f,0.f}, a1C = {0.f,0.f,0.f,0.f};

  // ---- prologue: acc = X(0) contribution ----
  {
    const us* xh = Xhi + (mrow << 9) + kj;
    const us* xl = Xlo + (mrow << 9) + kj;
    bf16x8 XA[8], XB[8];
    XISS(XA, 0) XISS(XB, 1)
    __builtin_amdgcn_sched_barrier(0);
    XCON2(XA, 0) XISS(XA, 2)
    __builtin_amdgcn_sched_barrier(0);
    XCON2(XB, 1) XISS(XB, 3)
    __builtin_amdgcn_sched_barrier(0);
    XCON2(XA, 2) XCON2(XB, 3)
  }

  #pragma unroll 1
  for (int t = 0; t < SSN; ++t) {
    if (t > 0) {
      if (ROT && (t & Km) == 0)
        __builtin_amdgcn_fence(__ATOMIC_ACQUIRE, "agent");  // ring wrap: drop stale L1/L2

      // ---- poll own plane's 128 flags (uncached dwordx4; lanes duplicated) ----
      {
        const int* fp = flagsP + ((lane & 31) << 2);
        int4v f;
        for (;;) {
          asm volatile("global_load_dwordx4 %0, %1, off sc0 sc1\n\t"
                       "s_waitcnt vmcnt(0)"
                       : "=&v"(f) : "v"(fp) : "memory");
          if (!__any((f.x < t) | (f.y < t) | (f.z < t) | (f.w < t))) break;
          __builtin_amdgcn_s_sleep(2);
        }
      }

      // ---- H part: cached loads (flag-gated => fresh), 4-deep pipeline ----
      const int cur = t & Km;
      const us* hh = Hhi + (((long)cur * BBN + mrow) << 10) + kj;
      const us* hl = Hlo + (((long)cur * BBN + mrow) << 10) + kj;
      bf16x8 HA[8], HB[8], HC[8], HD[8];
      HISS(HA, 0) HISS(HB, 1) HISS(HC, 2) HISS(HD, 3)
      __builtin_amdgcn_sched_barrier(0);
      HCON2(HA, 0) HISS(HA, 4)
      __builtin_amdgcn_sched_barrier(0);
      HCON2(HB, 1) HISS(HB, 5)
      __builtin_amdgcn_sched_barrier(0);
      HCON2(HC, 2) HISS(HC, 6)
      __builtin_amdgcn_sched_barrier(0);
      HCON2(HD, 3) HISS(HD, 7)
      __builtin_amdgcn_sched_barrier(0);
      HCON2(HA, 4) HCON2(HB, 5) HCON2(HC, 6) HCON2(HD, 7)
    }

    // ---- preact: two 16B LDS stores (v0 cols 0..16, v1 cols 16..32) ----
    {
      f32x4 s0 = a0A + a0B; s0 = s0 + a0C;
      f32x4 s1 = a1A + a1B; s1 = s1 + a1C;
      *(f32x4*)(preact + mrow * PST2 + p0)      = s0;
      *(f32x4*)(preact + mrow * PST2 + 16 + p0) = s1;
    }
    // no barrier: producer lanes and consumer threads are the SAME wave.

    // ---- gates: two (b,dim) pairs per thread ----
    {
      const float* pr = preact + gb * PST2;
      float pi0 = pr[gr]      + bi_0, pf0 = pr[4 + gr]  + bf_0;
      float po0 = pr[8 + gr]  + bo_0, pc0 = pr[12 + gr] + bc_0;
      float pi1 = pr[16 + gr] + bi_1, pf1 = pr[20 + gr] + bf_1;
      float po1 = pr[24 + gr] + bo_1, pc1 = pr[28 + gr] + bc_1;
      float vi0 = 1.f / (1.f + expf(-pi0)), vf0 = 1.f / (1.f + expf(-pf0));
      float vo0 = 1.f / (1.f + expf(-po0)), vc0 = tanhf(pc0);
      float vi1 = 1.f / (1.f + expf(-pi1)), vf1 = 1.f / (1.f + expf(-pf1));
      float vo1 = 1.f / (1.f + expf(-po1)), vc1 = tanhf(pc1);
      c0 = vf0 * c0 + vi0 * vc0;
      c1 = vf1 * c1 + vi1 * vc1;
      float h0 = vo0 * tanhf(c0);
      float h1 = vo1 * tanhf(c1);

      if (t == SSN - 1) {
        hfin[(gb << 10) + 8*j + gr]     = h0;
        hfin[(gb << 10) + 8*j + 4 + gr] = h1;
      } else {
        us h0h = f2bf(h0), h0l = f2bf(h0 - bf2f(h0h));
        us h1h = f2bf(h1), h1l = f2bf(h1 - bf2f(h1h));
        unsigned int hp0 = (unsigned int)h0h | ((unsigned int)h0l << 16);
        unsigned int hp1 = (unsigned int)h1h | ((unsigned int)h1l << 16);
        const int base = lane & ~3;
        unsigned int a0 = (unsigned int)__shfl((int)hp0, base);
        unsigned int a1 = (unsigned int)__shfl((int)hp0, base + 1);
        unsigned int a2 = (unsigned int)__shfl((int)hp0, base + 2);
        unsigned int a3 = (unsigned int)__shfl((int)hp0, base + 3);
        unsigned int b0 = (unsigned int)__shfl((int)hp1, base);
        unsigned int b1 = (unsigned int)__shfl((int)hp1, base + 1);
        unsigned int b2 = (unsigned int)__shfl((int)hp1, base + 2);
        unsigned int b3 = (unsigned int)__shfl((int)hp1, base + 3);
        unsigned int hi01 = (a0 & 0xffffu) | (a1 << 16), hi23 = (a2 & 0xffffu) | (a3 << 16);
        unsigned int hi45 = (b0 & 0xffffu) | (b1 << 16), hi67 = (b2 & 0xffffu) | (b3 << 16);
        unsigned int lo01 = (a0 >> 16) | (a1 & 0xffff0000u), lo23 = (a2 >> 16) | (a3 & 0xffff0000u);
        unsigned int lo45 = (b0 >> 16) | (b1 & 0xffff0000u), lo67 = (b2 >> 16) | (b3 & 0xffff0000u);
        ull hiq0 = ((ull)hi23 << 32) | hi01, hiq1 = ((ull)hi67 << 32) | hi45;
        ull loq0 = ((ull)lo23 << 32) | lo01, loq1 = ((ull)lo67 << 32) | lo45;

        const long nxt = (long)((t + 1) & Km);
        if (gr == 0) {
          us* ph = Hhi + ((nxt * BBN + gb) << 10) + 8*j;
          us* pl = Hlo + ((nxt * BBN + gb) << 10) + 8*j;
          __hip_atomic_store((ull*)ph,       hiq0, __ATOMIC_RELAXED, __HIP_MEMORY_SCOPE_AGENT);
          __hip_atomic_store((ull*)(ph + 4), hiq1, __ATOMIC_RELAXED, __HIP_MEMORY_SCOPE_AGENT);
          __hip_atomic_store((ull*)pl,       loq0, __ATOMIC_RELAXED, __HIP_MEMORY_SCOPE_AGENT);
          __hip_atomic_store((ull*)(pl + 4), loq1, __ATOMIC_RELAXED, __HIP_MEMORY_SCOPE_AGENT);
        }

        // ---- X(t+1): issue first chunks BEFORE the ack so the store-ack hides
        //      under X-load latency; flag right after; then MFMA (round-2 order).
        const us* xh = Xhi + ((long)(t + 1) << 15) + (mrow << 9) + kj;
        const us* xl = Xlo + ((long)(t + 1) << 15) + (mrow << 9) + kj;
        bf16x8 XA[8], XB[8];
        XISS(XA, 0) XISS(XB, 1)
        asm volatile("s_waitcnt vmcnt(0)" ::: "memory");  // h stores acked (wave counter)
        if (lane == 0)
          __hip_atomic_store(&flagsP[j], t + 1,
                             __ATOMIC_RELAXED, __HIP_MEMORY_SCOPE_AGENT);
        __builtin_amdgcn_sched_barrier(0);
        a0A = {0.f,0.f,0.f,0.f}; a0B = {0.f,0.f,0.f,0.f}; a0C = {0.f,0.f,0.f,0.f};
        a1A = {0.f,0.f,0.f,0.f}; a1B = {0.f,0.f,0.f,0.f}; a1C = {0.f,0.f,0.f,0.f};
        XCON2(XA, 0) XISS(XA, 2)
        __builtin_amdgcn_sched_barrier(0);
        XCON2(XB, 1) XISS(XB, 3)
        __builtin_amdgcn_sched_barrier(0);
        XCON2(XA, 2) XCON2(XB, 3)
      }
    }
  }
}

// ---------------- output GEMM: out = h_S @ W_hy + b_hy (fp32) ----------------
__global__ void out_gemm(const float* __restrict__ hfin, const float* __restrict__ Why,
                         const float* __restrict__ bhy, float* __restrict__ out) {
  int b = blockIdx.x, n = threadIdx.x;
  const float* h = hfin + (b << 10);
  float acc = 0.f;
  #pragma unroll 8
  for (int k = 0; k < HIDN; ++k) acc = fmaf(h[k], Why[(k << 9) + n], acc);
  out[(b << 9) + n] = acc + bhy[n];
}

// ---------------- launch ----------------
extern "C" void kernel_launch(void* const* d_in, const int* in_sizes, int n_in,
                              void* d_out, int out_size, void* d_ws, size_t ws_size,
                              hipStream_t stream) {
  const int*   tokens = (const int*)d_in[0];
  const float* emb    = (const float*)d_in[1];
  const float* Wxi    = (const float*)d_in[2];
  const float* Wxf    = (const float*)d_in[3];
  const float* Wxo    = (const float*)d_in[4];
  const float* Wxc    = (const float*)d_in[5];
  const float* Whi_   = (const float*)d_in[6];
  const float* Whf    = (const float*)d_in[7];
  const float* Who    = (const float*)d_in[8];
  const float* Whc    = (const float*)d_in[9];
  const float* Why    = (const float*)d_in[10];
  const float* bi     = (const float*)d_in[11];
  const float* bfv    = (const float*)d_in[12];
  const float* bo     = (const float*)d_in[13];
  const float* bc     = (const float*)d_in[14];
  const float* bhy    = (const float*)d_in[15];
  float* outp = (float*)d_out;

  char* ws = (char*)d_ws;
  size_t off = 0;
  auto carve = [&](size_t bytes) -> void* {
    void* p = ws + off;
    off += (bytes + 255) & ~(size_t)255;
    return p;
  };
  us*    Whip = (us*)carve(12582912);
  us*    Wlop = (us*)carve(12582912);
  us*    Xhi  = (us*)carve(16777216);
  us*    Xlo  = (us*)carve(16777216);
  float* hfin = (float*)carve(262144);
  int*   flags = (int*)carve(2048);            // [4 planes][128 blocks]

  // ring depth: largest power-of-two slot count (<=256) that fits.
  // K=256 -> zero reuse during the run (no fences at all).
  size_t rem = (ws_size > off) ? (ws_size - off) : 0;
  int K = 256;
  while (K > 8 && (size_t)2 * (size_t)K * 131072 + 512 > rem) K >>= 1;
  if ((size_t)2 * (size_t)K * 131072 + 512 > rem) {
    (void)hipMemsetAsync(d_out, 0, (size_t)out_size * 4, stream);  // workspace too small
    return;
  }
  us* Hhi = (us*)carve((size_t)K * 131072);
  us* Hlo = (us*)carve((size_t)K * 131072);

  (void)hipMemsetAsync(flags, 0, 2048, stream);

  pack_w<<<3072, 256, 0, stream>>>(Wxi, Wxf, Wxo, Wxc, Whi_, Whf, Who, Whc, Whip, Wlop);
  pack_x<<<32768, 256, 0, stream>>>(tokens, emb, Xhi, Xlo);

  (void)hipFuncSetAttribute((const void*)lstm_persist,
                            hipFuncAttributeMaxDynamicSharedMemorySize, 160768);
  lstm_persist<<<NBLK, 256, 160768, stream>>>(Whip, Wlop, Xhi, Xlo, Hhi, Hlo,
                                              hfin, flags, bi, bfv, bo, bc, K);
  out_gemm<<<BBN, OUTN, 0, stream>>>(hfin, Why, bhy, outp);
}

// Round 12
// 2851.158 us; speedup vs baseline: 2.9766x; 1.0247x over previous
//
#include <hip/hip_runtime.h>
#include <hip/hip_bf16.h>

// ---------------- problem constants ----------------
#define EMBN   512
#define HIDN   1024
#define OUTN   512
#define BBN    64
#define SSN    256
#define NBLK   256          // persistent blocks; block j owns 4 h-dims x 4 gates = 16 preact cols
#define PSTR   20           // preact LDS row stride (floats)

typedef __attribute__((ext_vector_type(8))) short bf16x8;
typedef __attribute__((ext_vector_type(4))) float f32x4;
typedef __attribute__((ext_vector_type(4))) int int4v;
typedef unsigned short us;
typedef unsigned long long ull;

static __device__ __forceinline__ us f2bf(float x) {
  unsigned int u = __float_as_uint(x);
  unsigned int r = (u + 0x7fffu + ((u >> 16) & 1u)) >> 16;   // RNE
  return (us)r;
}
static __device__ __forceinline__ float bf2f(us u) {
  unsigned int v = ((unsigned int)u) << 16;
  return __uint_as_float(v);
}

// ---------------- weight prepack: [j(256)][kt(48)][lane(64)][8] ----------------
// block j owns preact cols p = 16j+q, q in [0,16): gate g=q>>2, r=q&3, hd=4j+r
__global__ void pack_w(const float* __restrict__ wxi, const float* __restrict__ wxf,
                       const float* __restrict__ wxo, const float* __restrict__ wxc,
                       const float* __restrict__ whi, const float* __restrict__ whf,
                       const float* __restrict__ who, const float* __restrict__ whc,
                       us* __restrict__ Whip, us* __restrict__ Wlop) {
  int idx = blockIdx.x * 256 + threadIdx.x;       // 256*48*64 = 786432
  int lane = idx & 63;
  int kt   = (idx >> 6) % 48;
  int j    = idx / (48 * 64);
  int q = lane & 15, g = q >> 2, r = q & 3;
  int hd = 4 * j + r;
  int kb = kt * 32 + ((lane >> 4) << 3);
  const float* wx = (g == 0) ? wxi : (g == 1) ? wxf : (g == 2) ? wxo : wxc;
  const float* wh = (g == 0) ? whi : (g == 1) ? whf : (g == 2) ? who : whc;
  long obase = (long)idx * 8;
  #pragma unroll
  for (int jj = 0; jj < 8; ++jj) {
    int k = kb + jj;
    float v = (k < EMBN) ? wx[(long)k * HIDN + hd] : wh[(long)(k - EMBN) * HIDN + hd];
    us hi = f2bf(v);
    us lo = f2bf(v - bf2f(hi));
    Whip[obase + jj] = hi;
    Wlop[obase + jj] = lo;
  }
}

// ---------------- embedding gather + hi/lo split: X[t][b][k] ----------------
__global__ void pack_x(const int* __restrict__ tokens, const float* __restrict__ emb,
                       us* __restrict__ Xhi, us* __restrict__ Xlo) {
  int idx = blockIdx.x * 256 + threadIdx.x;       // 256*64*512 = 8388608
  int k = idx & 511;
  int b = (idx >> 9) & 63;
  int t = idx >> 15;
  int tok = tokens[b * SSN + t];
  float v = emb[(long)tok * EMBN + k];
  us hi = f2bf(v);
  Xhi[idx] = hi;
  Xlo[idx] = f2bf(v - bf2f(hi));
}

// chunk = 4 kt (4 hi + 4 lo frags = 8 bf16x8 = 32 VGPR)
#define XISS(A, c) { _Pragma("unroll") for (int q = 0; q < 4; ++q) { \
      A[2*q]   = *(const bf16x8*)(xh + (((c)*4 + q) << 5)); \
      A[2*q+1] = *(const bf16x8*)(xl + (((c)*4 + q) << 5)); } }
#define XCON(A, c) { _Pragma("unroll") for (int q = 0; q < 4; ++q) { \
      const int kt = (c)*4 + q; \
      bf16x8 w0 = *(const bf16x8*)(WHi + (kt << 9) + (lane << 3)); \
      bf16x8 w1 = *(const bf16x8*)(WLo + (kt << 9) + (lane << 3)); \
      accA = __builtin_amdgcn_mfma_f32_16x16x32_bf16(w0, A[2*q],   accA, 0, 0, 0); \
      accB = __builtin_amdgcn_mfma_f32_16x16x32_bf16(w0, A[2*q+1], accB, 0, 0, 0); \
      accC = __builtin_amdgcn_mfma_f32_16x16x32_bf16(w1, A[2*q],   accC, 0, 0, 0); } }
#define HISS(A, c) { _Pragma("unroll") for (int q = 0; q < 4; ++q) { \
      A[2*q]   = *(const bf16x8*)(hh + (((c)*4 + q) << 5)); \
      A[2*q+1] = *(const bf16x8*)(hl + (((c)*4 + q) << 5)); } }
#define HCON(A, c) { _Pragma("unroll") for (int q = 0; q < 4; ++q) { \
      const int kt = 16 + (c)*4 + q; \
      bf16x8 w0 = *(const bf16x8*)(WHi + (kt << 9) + (lane << 3)); \
      bf16x8 w1 = *(const bf16x8*)(WLo + (kt << 9) + (lane << 3)); \
      accA = __builtin_amdgcn_mfma_f32_16x16x32_bf16(w0, A[2*q],   accA, 0, 0, 0); \
      accB = __builtin_amdgcn_mfma_f32_16x16x32_bf16(w0, A[2*q+1], accB, 0, 0, 0); \
      accC = __builtin_amdgcn_mfma_f32_16x16x32_bf16(w1, A[2*q],   accC, 0, 0, 0); } }

// ---------------- persistent LSTM recurrence + heater waves ----------------
// ROUND-11: round-2 structure byte-identical (best verified, 2821us) for waves
// 0..3; waves 4..7 are HEATERS: endless dependent-FMA chains, one per SIMD.
// Rationale: MfmaUtil 8.6% with 700 MFMA-busy cycles/step implies the step is
// ~8.1K cycles, but wall time is 11.4us -> effective clock ~730 MHz. The ~90%-
// idle kernel sits in the idle P-state and every fabric leg costs ~3x in wall
// time. Heaters keep all 4 SIMDs VALU-busy during main-wave stalls (poll,
// vmcnt, lgkm), signaling the DVFS governor to hold boost clocks. Main waves
// run at s_setprio(2) so heaters only consume issue slots mains don't want.
__launch_bounds__(512, 1)
__global__ void lstm_persist(const us* __restrict__ Whip, const us* __restrict__ Wlop,
                             const us* __restrict__ Xhi, const us* __restrict__ Xlo,
                             us* Hhi, us* Hlo, float* hfin, int* flags,
                             const float* __restrict__ biP, const float* __restrict__ bfP,
                             const float* __restrict__ boP, const float* __restrict__ bcP,
                             int K) {
  extern __shared__ char smem[];
  us* WHi = (us*)smem;                         // 24576 shorts
  us* WLo = WHi + 24576;                       // 24576 shorts
  float* preact = (float*)(smem + 98304);      // [64][PSTR], rows partition by wave
  int* done = (int*)(smem + 103424);           // heater exit counter

  const int j = blockIdx.x, tid = threadIdx.x;
  const int wv = tid >> 6, lane = tid & 63;
  const int Km = K - 1;
  const bool ROT = (K != 256);

  // one-time: W slices -> LDS (all 8 waves participate)
  {
    const uint4* shi = (const uint4*)(Whip + (long)j * 24576);
    const uint4* slo = (const uint4*)(Wlop + (long)j * 24576);
    uint4* dhi = (uint4*)WHi;
    uint4* dlo = (uint4*)WLo;
    for (int i = tid; i < 3072; i += 512) { dhi[i] = shi[i]; dlo[i] = slo[i]; }
  }
  if (tid == 0) *done = 0;
  __syncthreads();                             // W in LDS + done init (only barrier)

  if (wv >= 4) {
    // ---- heater wave: dependent FMA chain; exits when all 4 mains finish ----
    float a = 1.0f;
    const float bmul = 1.0000001f, cadd = 1e-7f;
    for (;;) {
      #pragma unroll
      for (int z = 0; z < 128; ++z) a = fmaf(a, bmul, cadd);
      asm volatile("" : "+v"(a));              // keep chain live (no DCE/hoist)
      if (__hip_atomic_load(done, __ATOMIC_RELAXED, __HIP_MEMORY_SCOPE_WORKGROUP) >= 4)
        break;
    }
    return;
  }

  __builtin_amdgcn_s_setprio(2);               // mains outrank heaters on issue

  // gate mapping: thread -> (b = tid>>2, r = tid&3); c-state in register.
  const int gb = tid >> 2, gr = tid & 3;
  const float bi_r = biP[4 * j + gr], bf_r = bfP[4 * j + gr];
  const float bo_r = boP[4 * j + gr], bc_r = bcP[4 * j + gr];
  float c_reg = 0.f;

  const int mrow = (wv << 4) + (lane & 15);    // batch row (MFMA N-dim)
  const int kj = (lane >> 4) << 3;
  const int p0 = (lane >> 4) << 2;
  int* const flagsP = flags + (wv << 8);       // this plane's 256 flags

  f32x4 accA = {0.f, 0.f, 0.f, 0.f};
  f32x4 accB = {0.f, 0.f, 0.f, 0.f};
  f32x4 accC = {0.f, 0.f, 0.f, 0.f};

  // ---- prologue: acc = X(0) contribution ----
  {
    const us* xh = Xhi + (mrow << 9) + kj;
    const us* xl = Xlo + (mrow << 9) + kj;
    bf16x8 XA[8], XB[8];
    XISS(XA, 0) XISS(XB, 1)
    __builtin_amdgcn_sched_barrier(0);
    XCON(XA, 0) XISS(XA, 2)
    __builtin_amdgcn_sched_barrier(0);
    XCON(XB, 1) XISS(XB, 3)
    __builtin_amdgcn_sched_barrier(0);
    XCON(XA, 2) XCON(XB, 3)
  }

  #pragma unroll 1
  for (int t = 0; t < SSN; ++t) {
    if (t > 0) {
      if (ROT && (t & Km) == 0)
        __builtin_amdgcn_fence(__ATOMIC_ACQUIRE, "agent");  // ring wrap: drop stale lines

      // ---- poll own plane's 256 flags (uncached dwordx4 per lane) ----
      {
        const int* fp = flagsP + (lane << 2);
        int4v f;
        for (;;) {
          asm volatile("global_load_dwordx4 %0, %1, off sc0 sc1\n\t"
                       "s_waitcnt vmcnt(0)"
                       : "=&v"(f) : "v"(fp) : "memory");
          if (!__any((f.x < t) | (f.y < t) | (f.z < t) | (f.w < t))) break;
          __builtin_amdgcn_s_sleep(2);
        }
      }

      // ---- H part: cached loads (flag-gated => lines fresh), 4-deep pipeline ----
      const int cur = t & Km;
      const us* hh = Hhi + (((long)cur * BBN + mrow) << 10) + kj;
      const us* hl = Hlo + (((long)cur * BBN + mrow) << 10) + kj;
      bf16x8 HA[8], HB[8], HC[8], HD[8];
      HISS(HA, 0) HISS(HB, 1) HISS(HC, 2) HISS(HD, 3)
      __builtin_amdgcn_sched_barrier(0);
      HCON(HA, 0) HISS(HA, 4)
      __builtin_amdgcn_sched_barrier(0);
      HCON(HB, 1) HISS(HB, 5)
      __builtin_amdgcn_sched_barrier(0);
      HCON(HC, 2) HISS(HC, 6)
      __builtin_amdgcn_sched_barrier(0);
      HCON(HD, 3) HISS(HD, 7)
      __builtin_amdgcn_sched_barrier(0);
      HCON(HA, 4) HCON(HB, 5) HCON(HC, 6) HCON(HD, 7)
    }

    // ---- preact: lane holds D[p0+rg][mrow]; 16B LDS store (intra-wave rows) ----
    {
      f32x4 acc = accA + accB;
      acc = acc + accC;
      *(f32x4*)(preact + mrow * PSTR + p0) = acc;
    }
    // no barrier: producer lanes and consumer threads are the SAME wave;
    // compiler orders ds_write -> ds_read via lgkmcnt.

    // ---- gates: one (b,r) per thread ----
    {
      float pi = preact[gb * PSTR + gr]      + bi_r;
      float pf = preact[gb * PSTR + 4 + gr]  + bf_r;
      float po = preact[gb * PSTR + 8 + gr]  + bo_r;
      float pc = preact[gb * PSTR + 12 + gr] + bc_r;
      float vi = 1.f / (1.f + expf(-pi));
      float vf = 1.f / (1.f + expf(-pf));
      float vo = 1.f / (1.f + expf(-po));
      float vc = tanhf(pc);
      c_reg = vf * c_reg + vi * vc;
      float h = vo * tanhf(c_reg);

      if (t == SSN - 1) {
        hfin[(gb << 10) + 4 * j + gr] = h;     // last step: only the final h matters
      } else {
        us hh_ = f2bf(h);
        us hl_ = f2bf(h - bf2f(hh_));
        // pack (hi,lo) of the 4 dims of this lane-group into two 8B quads
        unsigned int hpair = (unsigned int)hh_ | ((unsigned int)hl_ << 16);
        const int base = lane & ~3;
        unsigned int g0 = (unsigned int)__shfl((int)hpair, base);
        unsigned int g1 = (unsigned int)__shfl((int)hpair, base + 1);
        unsigned int g2 = (unsigned int)__shfl((int)hpair, base + 2);
        unsigned int g3 = (unsigned int)__shfl((int)hpair, base + 3);
        unsigned int hi01 = (g0 & 0xffffu) | (g1 << 16);
        unsigned int hi23 = (g2 & 0xffffu) | (g3 << 16);
        unsigned int lo01 = (g0 >> 16)     | (g1 & 0xffff0000u);
        unsigned int lo23 = (g2 >> 16)     | (g3 & 0xffff0000u);
        ull hiq = ((ull)hi23 << 32) | (ull)hi01;
        ull loq = ((ull)lo23 << 32) | (ull)lo01;

        const long nxt = (long)((t + 1) & Km);
        if (gr == 0) {
          __hip_atomic_store((ull*)(Hhi + ((nxt * BBN + gb) << 10) + 4 * j), hiq,
                             __ATOMIC_RELAXED, __HIP_MEMORY_SCOPE_AGENT);
          __hip_atomic_store((ull*)(Hlo + ((nxt * BBN + gb) << 10) + 4 * j), loq,
                             __ATOMIC_RELAXED, __HIP_MEMORY_SCOPE_AGENT);
        }

        // ---- X part for t+1: issue first 2 chunks BEFORE the ack wait so the
        //      store-ack hides under X-load latency; flag right after; then MFMA.
        const us* xh = Xhi + ((long)(t + 1) << 15) + (mrow << 9) + kj;
        const us* xl = Xlo + ((long)(t + 1) << 15) + (mrow << 9) + kj;
        bf16x8 XA[8], XB[8];
        XISS(XA, 0) XISS(XB, 1)
        asm volatile("s_waitcnt vmcnt(0)" ::: "memory");  // h stores acked (wave counter)
        if (lane == 0)
          __hip_atomic_store(&flagsP[j], t + 1,
                             __ATOMIC_RELAXED, __HIP_MEMORY_SCOPE_AGENT);
        __builtin_amdgcn_sched_barrier(0);
        accA = {0.f, 0.f, 0.f, 0.f};
        accB = {0.f, 0.f, 0.f, 0.f};
        accC = {0.f, 0.f, 0.f, 0.f};
        XCON(XA, 0) XISS(XA, 2)
        __builtin_amdgcn_sched_barrier(0);
        XCON(XB, 1) XISS(XB, 3)
        __builtin_amdgcn_sched_barrier(0);
        XCON(XA, 2) XCON(XB, 3)
      }
    }
  }

  // signal heaters on this CU to exit
  if (lane == 0)
    __hip_atomic_fetch_add(done, 1, __ATOMIC_RELAXED, __HIP_MEMORY_SCOPE_WORKGROUP);
}

// ---------------- output GEMM: out = h_S @ W_hy + b_hy (fp32) ----------------
__global__ void out_gemm(const float* __restrict__ hfin, const float* __restrict__ Why,
                         const float* __restrict__ bhy, float* __restrict__ out) {
  int b = blockIdx.x, n = threadIdx.x;
  const float* h = hfin + (b << 10);
  float acc = 0.f;
  #pragma unroll 8
  for (int k = 0; k < HIDN; ++k) acc = fmaf(h[k], Why[(k << 9) + n], acc);
  out[(b << 9) + n] = acc + bhy[n];
}

// ---------------- launch ----------------
extern "C" void kernel_launch(void* const* d_in, const int* in_sizes, int n_in,
                              void* d_out, int out_size, void* d_ws, size_t ws_size,
                              hipStream_t stream) {
  const int*   tokens = (const int*)d_in[0];
  const float* emb    = (const float*)d_in[1];
  const float* Wxi    = (const float*)d_in[2];
  const float* Wxf    = (const float*)d_in[3];
  const float* Wxo    = (const float*)d_in[4];
  const float* Wxc    = (const float*)d_in[5];
  const float* Whi_   = (const float*)d_in[6];
  const float* Whf    = (const float*)d_in[7];
  const float* Who    = (const float*)d_in[8];
  const float* Whc    = (const float*)d_in[9];
  const float* Why    = (const float*)d_in[10];
  const float* bi     = (const float*)d_in[11];
  const float* bfv    = (const float*)d_in[12];
  const float* bo     = (const float*)d_in[13];
  const float* bc     = (const float*)d_in[14];
  const float* bhy    = (const float*)d_in[15];
  float* outp = (float*)d_out;

  char* ws = (char*)d_ws;
  size_t off = 0;
  auto carve = [&](size_t bytes) -> void* {
    void* p = ws + off;
    off += (bytes + 255) & ~(size_t)255;
    return p;
  };
  us*    Whip = (us*)carve(12582912);
  us*    Wlop = (us*)carve(12582912);
  us*    Xhi  = (us*)carve(16777216);
  us*    Xlo  = (us*)carve(16777216);
  float* hfin = (float*)carve(262144);
  int*   flags = (int*)carve(4096);            // [4 planes][256 blocks]

  // ring depth: largest power-of-two slot count (<=256) that fits.
  // K=256 -> zero reuse during the run (no fences at all).
  size_t rem = (ws_size > off) ? (ws_size - off) : 0;
  int K = 256;
  while (K > 8 && (size_t)2 * (size_t)K * 131072 + 512 > rem) K >>= 1;
  if ((size_t)2 * (size_t)K * 131072 + 512 > rem) {
    (void)hipMemsetAsync(d_out, 0, (size_t)out_size * 4, stream);  // workspace too small
    return;
  }
  us* Hhi = (us*)carve((size_t)K * 131072);
  us* Hlo = (us*)carve((size_t)K * 131072);

  (void)hipMemsetAsync(flags, 0, 4096, stream);

  pack_w<<<3072, 256, 0, stream>>>(Wxi, Wxf, Wxo, Wxc, Whi_, Whf, Who, Whc, Whip, Wlop);
  pack_x<<<32768, 256, 0, stream>>>(tokens, emb, Xhi, Xlo);

  (void)hipFuncSetAttribute((const void*)lstm_persist,
                            hipFuncAttributeMaxDynamicSharedMemorySize, 103440);
  lstm_persist<<<NBLK, 512, 103440, stream>>>(Whip, Wlop, Xhi, Xlo, Hhi, Hlo,
                                              hfin, flags, bi, bfv, bo, bc, K);
  out_gemm<<<BBN, OUTN, 0, stream>>>(hfin, Why, bhy, outp);
}